// Round 1
// baseline (258.129 us; speedup 1.0000x reference)
//
#include <hip/hip_runtime.h>
#include <hip/hip_bf16.h>

// BertCrf: B=64, S=512, H=768, L=9
// Stage 1: feats[b,s,l] = dot(hidden[b,s,:], W[l,:]) + bias[l]   (HBM-bound, 96MB read)
// Stage 2: per-b CRF forward (latency-bound serial over S) + numerator score
// Stage 3: mean over B
#define BB 64
#define SS 512
#define HH 768
#define LL 9

#if __has_builtin(__builtin_amdgcn_exp2f)
#define EXP2F(x) __builtin_amdgcn_exp2f(x)
#else
#define EXP2F(x) exp2f(x)
#endif
#if __has_builtin(__builtin_amdgcn_logf)
#define LOG2F(x) __builtin_amdgcn_logf(x)
#else
#define LOG2F(x) __log2f(x)
#endif

static __device__ __forceinline__ float dot4(float4 a, float4 b) {
    return a.x * b.x + a.y * b.y + a.z * b.z + a.w * b.w;
}

// One wave per row. W held entirely in registers (9 x 12 floats per lane = 108 VGPR).
// 3 coalesced float4 loads of the hidden row per lane, 108 FMA, 9 butterfly reduces.
__global__ __launch_bounds__(256, 2)
void feats_kernel(const float* __restrict__ hidden,
                  const float* __restrict__ W,
                  const float* __restrict__ bias,
                  float* __restrict__ feats) {
    const int lane = threadIdx.x & 63;
    const int wv   = threadIdx.x >> 6;
    const int gw   = blockIdx.x * (blockDim.x >> 6) + wv;
    const int nw   = gridDim.x * (blockDim.x >> 6);

    float4 wreg[3][LL];
#pragma unroll
    for (int c = 0; c < 3; ++c)
#pragma unroll
        for (int l = 0; l < LL; ++l)
            wreg[c][l] = *(const float4*)(W + l * HH + c * 256 + (lane << 2));

    const float bv = bias[lane < LL ? lane : 0];

    const int R = BB * SS;
    for (int row = gw; row < R; row += nw) {
        const float4* hrow = (const float4*)(hidden + (size_t)row * HH);
        float4 h0 = hrow[lane];
        float4 h1 = hrow[64 + lane];
        float4 h2 = hrow[128 + lane];
        float acc[LL];
#pragma unroll
        for (int l = 0; l < LL; ++l)
            acc[l] = dot4(h0, wreg[0][l]) + dot4(h1, wreg[1][l]) + dot4(h2, wreg[2][l]);
        // full-wave butterfly sum for each of the 9 outputs
#pragma unroll
        for (int l = 0; l < LL; ++l) {
            float v = acc[l];
#pragma unroll
            for (int off = 1; off < 64; off <<= 1)
                v += __shfl_xor(v, off);
            acc[l] = v;
        }
        float out = 0.f;
#pragma unroll
        for (int l = 0; l < LL; ++l)      // static indexing: keep acc in registers
            if (lane == l) out = acc[l];
        if (lane < LL)
            feats[(size_t)row * LL + lane] = out + bv;
    }
}

// One wave per batch element. Lane j (j<9) owns state j.
// alpha kept in log2 domain; rebroadcast each step via v_readlane.
// Score (numerator) computed first by all 64 lanes (also yields len via popcount).
__global__ __launch_bounds__(64, 1)
void crf_kernel(const float* __restrict__ feats,
                const float* __restrict__ start_t,
                const float* __restrict__ end_t,
                const float* __restrict__ trans,
                const int* __restrict__ labels,
                const int* __restrict__ mask,
                float* __restrict__ nll_out) {
    const int b    = blockIdx.x;
    const int lane = threadIdx.x;
    const int j    = lane < LL ? lane : LL - 1;
    const float INV_LN2 = 1.4426950408889634f;
    const float LN2     = 0.6931471805599453f;

    const float* fb = feats + (size_t)b * SS * LL;
    const int*   lb = labels + b * SS;
    const int*   mb = mask + b * SS;

    // ---- numerator score + sequence length (all 64 lanes, strided over t) ----
    float partial = 0.f;
    int   cnt     = 0;
    for (int t = lane; t < SS; t += 64) {
        const int m = mb[t];
        cnt += (m != 0);
        if (t >= 1 && m) {
            const int lp = lb[t - 1], lc = lb[t];
            partial += trans[lp * LL + lc] + fb[t * LL + lc];
        }
    }
#pragma unroll
    for (int off = 1; off < 64; off <<= 1) {
        partial += __shfl_xor(partial, off);
        cnt     += __shfl_xor(cnt, off);
    }

    // ---- forward recursion (mask is monotone: run t in [1, cnt)) ----
    float trC[LL];
#pragma unroll
    for (int i = 0; i < LL; ++i) trC[i] = trans[i * LL + j] * INV_LN2;

    float alpha[LL];
#pragma unroll
    for (int i = 0; i < LL; ++i) alpha[i] = (start_t[i] + fb[i]) * INV_LN2;

    float fnext = fb[LL + j];   // emission for t=1, prefetched
    for (int t = 1; t < cnt; ++t) {
        const float f = fnext * INV_LN2;
        const int tn = (t + 1 < SS) ? t + 1 : SS - 1;
        fnext = fb[tn * LL + j];            // prefetch next step off the chain
        float v[LL];
#pragma unroll
        for (int i = 0; i < LL; ++i) v[i] = alpha[i] + trC[i];
        float mx = v[0];
#pragma unroll
        for (int i = 1; i < LL; ++i) mx = fmaxf(mx, v[i]);
        float s = 0.f;
#pragma unroll
        for (int i = 0; i < LL; ++i) s += EXP2F(v[i] - mx);
        const float anew = f + mx + LOG2F(s);
#pragma unroll
        for (int i = 0; i < LL; ++i)
            alpha[i] = __uint_as_float(__builtin_amdgcn_readlane(__float_as_uint(anew), i));
    }

    // ---- log_den = LSE(alpha + end) ----
    float v[LL];
#pragma unroll
    for (int i = 0; i < LL; ++i) v[i] = alpha[i] + end_t[i] * INV_LN2;
    float mx = v[0];
#pragma unroll
    for (int i = 1; i < LL; ++i) mx = fmaxf(mx, v[i]);
    float s = 0.f;
#pragma unroll
    for (int i = 0; i < LL; ++i) s += EXP2F(v[i] - mx);
    const float log_den = (mx + LOG2F(s)) * LN2;

    if (lane == 0) {
        const int l0 = lb[0];
        const float score = start_t[l0] + fb[l0] + partial + end_t[lb[cnt - 1]];
        nll_out[b] = log_den - score;
    }
}

__global__ __launch_bounds__(64, 1)
void mean_kernel(const float* __restrict__ nll, float* __restrict__ out) {
    float v = nll[threadIdx.x];
#pragma unroll
    for (int off = 1; off < 64; off <<= 1)
        v += __shfl_xor(v, off);
    if (threadIdx.x == 0) out[0] = v * (1.0f / BB);
}

extern "C" void kernel_launch(void* const* d_in, const int* in_sizes, int n_in,
                              void* d_out, int out_size, void* d_ws, size_t ws_size,
                              hipStream_t stream) {
    const float* hidden = (const float*)d_in[0];
    const float* W      = (const float*)d_in[1];
    const float* bias   = (const float*)d_in[2];
    const float* startT = (const float*)d_in[3];
    const float* endT   = (const float*)d_in[4];
    const float* trans  = (const float*)d_in[5];
    const int*   labels = (const int*)d_in[6];
    const int*   mask   = (const int*)d_in[7];   // bool -> int32 per harness convention

    float* feats = (float*)d_ws;                 // B*S*L fp32 = 1.18 MB
    float* nll   = feats + (size_t)BB * SS * LL; // 64 fp32

    feats_kernel<<<dim3(1024), dim3(256), 0, stream>>>(hidden, W, bias, feats);
    crf_kernel<<<dim3(BB), dim3(64), 0, stream>>>(feats, startT, endT, trans, labels, mask, nll);
    mean_kernel<<<dim3(1), dim3(64), 0, stream>>>(nll, (float*)d_out);
}

// Round 2
// 202.274 us; speedup vs baseline: 1.2761x; 1.2761x over previous
//
#include <hip/hip_runtime.h>
#include <hip/hip_bf16.h>

// BertCrf: B=64, S=512, H=768, L=9
// Stage 1: feats[b,s,l] = dot(hidden[b,s,:], W[l,:]) + bias[l]   (HBM-bound, 96MB read)
// Stage 2a: per-(b,chunk) log-semiring matrix product of 16 transition matrices (parallel)
// Stage 2b: per-b fold of 32 chunk matrices into alpha + numerator score (serial but tiny)
// Stage 3: mean over B
#define BB 64
#define SS 512
#define HH 768
#define LL 9
#define CL 16              // chunk length (time steps per chunk)
#define NC (SS / CL)       // 32 chunks
#define NEG (-1e30f)

#if __has_builtin(__builtin_amdgcn_exp2f)
#define EXP2F(x) __builtin_amdgcn_exp2f(x)
#else
#define EXP2F(x) exp2f(x)
#endif
#if __has_builtin(__builtin_amdgcn_logf)
#define LOG2F(x) __builtin_amdgcn_logf(x)
#else
#define LOG2F(x) __log2f(x)
#endif

static __device__ __forceinline__ float dot4(float4 a, float4 b) {
    return a.x * b.x + a.y * b.y + a.z * b.z + a.w * b.w;
}

static __device__ __forceinline__ float max9(const float* v) {
    float m1 = fmaxf(fmaxf(v[0], v[1]), v[2]);
    float m2 = fmaxf(fmaxf(v[3], v[4]), v[5]);
    float m3 = fmaxf(fmaxf(v[6], v[7]), v[8]);
    return fmaxf(fmaxf(m1, m2), m3);   // compiler fuses to v_max3_f32
}

// ---------------- Stage 1: emissions ----------------
__global__ __launch_bounds__(256, 2)
void feats_kernel(const float* __restrict__ hidden,
                  const float* __restrict__ W,
                  const float* __restrict__ bias,
                  float* __restrict__ feats) {
    const int lane = threadIdx.x & 63;
    const int wv   = threadIdx.x >> 6;
    const int gw   = blockIdx.x * (blockDim.x >> 6) + wv;
    const int nw   = gridDim.x * (blockDim.x >> 6);

    float4 wreg[3][LL];
#pragma unroll
    for (int c = 0; c < 3; ++c)
#pragma unroll
        for (int l = 0; l < LL; ++l)
            wreg[c][l] = *(const float4*)(W + l * HH + c * 256 + (lane << 2));

    const float bv = bias[lane < LL ? lane : 0];

    const int R = BB * SS;
    for (int row = gw; row < R; row += nw) {
        const float4* hrow = (const float4*)(hidden + (size_t)row * HH);
        float4 h0 = hrow[lane];
        float4 h1 = hrow[64 + lane];
        float4 h2 = hrow[128 + lane];
        float acc[LL];
#pragma unroll
        for (int l = 0; l < LL; ++l)
            acc[l] = dot4(h0, wreg[0][l]) + dot4(h1, wreg[1][l]) + dot4(h2, wreg[2][l]);
#pragma unroll
        for (int l = 0; l < LL; ++l) {
            float v = acc[l];
#pragma unroll
            for (int off = 1; off < 64; off <<= 1)
                v += __shfl_xor(v, off);
            acc[l] = v;
        }
        float out = 0.f;
#pragma unroll
        for (int l = 0; l < LL; ++l)
            if (lane == l) out = acc[l];
        if (lane < LL)
            feats[(size_t)row * LL + lane] = out + bv;
    }
}

// ---------------- Stage 2a: chunked log-semiring matrix products ----------------
// Block = 192 threads; lane (i,j) at tid = i*16 + j holds running product P[i][j].
// Rows live in 16-lane groups so the row gather is in-wave __shfl (4 rows/wave).
// Masked steps (m==0) are identity; mask is monotone so run first `na` steps only.
__global__ __launch_bounds__(192, 2)
void crf_chunk_kernel(const float* __restrict__ feats,
                      const float* __restrict__ trans,
                      const int* __restrict__ mask,
                      float* __restrict__ Q) {
    const float INV_LN2 = 1.4426950408889634f;
    const int b   = blockIdx.x / NC;
    const int c   = blockIdx.x % NC;
    const int tid = threadIdx.x;
    const int i   = tid >> 4;          // row (0..11; >=9 inactive)
    const int j   = tid & 15;          // col (0..15; >=9 inactive)
    const int jc  = j < LL ? j : LL - 1;

    float trC[LL];
#pragma unroll
    for (int k = 0; k < LL; ++k) trC[k] = trans[k * LL + jc] * INV_LN2;

    const int t0    = (c == 0) ? 1 : c * CL;
    const int steps = (c + 1) * CL - t0;       // 15 or 16

    const float* fb = feats + (size_t)b * SS * LL;
    const int*   mb = mask + b * SS;

    float fs[CL];
    int   na = 0;
#pragma unroll
    for (int s = 0; s < CL; ++s) {
        if (s < steps) {
            const int t = t0 + s;
            fs[s] = fb[t * LL + jc] * INV_LN2;
            na += (mb[t] != 0) ? 1 : 0;
        } else {
            fs[s] = 0.f;
        }
    }

    float P = (i == j) ? 0.f : NEG;            // identity in log-semiring

    for (int s = 0; s < na; ++s) {
        float v[LL];
#pragma unroll
        for (int k = 0; k < LL; ++k)
            v[k] = __shfl(P, ((i & 3) << 4) | k) + trC[k];
        const float mx = max9(v);
        float sum = 0.f;
#pragma unroll
        for (int k = 0; k < LL; ++k) sum += EXP2F(v[k] - mx);
        P = mx + LOG2F(sum) + fs[s];
    }

    if (i < LL && j < LL)
        Q[((size_t)(b * NC + c)) * (LL * LL) + i * LL + j] = P;
}

// ---------------- Stage 2b: fold chunks + numerator score ----------------
__global__ __launch_bounds__(64, 1)
void crf_combine_kernel(const float* __restrict__ feats,
                        const float* __restrict__ Q,
                        const float* __restrict__ start_t,
                        const float* __restrict__ end_t,
                        const float* __restrict__ trans,
                        const int* __restrict__ labels,
                        const int* __restrict__ mask,
                        float* __restrict__ nll_out) {
    const int b    = blockIdx.x;
    const int lane = threadIdx.x;
    const int j    = lane < LL ? lane : LL - 1;
    const float INV_LN2 = 1.4426950408889634f;
    const float LN2     = 0.6931471805599453f;

    const float* fb = feats + (size_t)b * SS * LL;
    const int*   lb = labels + b * SS;
    const int*   mb = mask + b * SS;
    const float* Qb = Q + (size_t)b * NC * (LL * LL);

    // numerator score + sequence length
    float partial = 0.f;
    int   cnt     = 0;
    for (int t = lane; t < SS; t += 64) {
        const int m = mb[t];
        cnt += (m != 0);
        if (t >= 1 && m) {
            const int lp = lb[t - 1], lc = lb[t];
            partial += trans[lp * LL + lc] + fb[t * LL + lc];
        }
    }
#pragma unroll
    for (int off = 1; off < 64; off <<= 1) {
        partial += __shfl_xor(partial, off);
        cnt     += __shfl_xor(cnt, off);
    }

    // alpha0, then fold the 32 chunk matrices
    float alpha[LL];
#pragma unroll
    for (int k = 0; k < LL; ++k) alpha[k] = (start_t[k] + fb[k]) * INV_LN2;

    float qcol[LL], qnext[LL];
#pragma unroll
    for (int k = 0; k < LL; ++k) qnext[k] = Qb[k * LL + j];
    for (int c = 0; c < NC; ++c) {
#pragma unroll
        for (int k = 0; k < LL; ++k) qcol[k] = qnext[k];
        if (c + 1 < NC) {
            const float* Qn = Qb + (size_t)(c + 1) * (LL * LL);
#pragma unroll
            for (int k = 0; k < LL; ++k) qnext[k] = Qn[k * LL + j];
        }
        float v[LL];
#pragma unroll
        for (int k = 0; k < LL; ++k) v[k] = alpha[k] + qcol[k];
        const float mx = max9(v);
        float sum = 0.f;
#pragma unroll
        for (int k = 0; k < LL; ++k) sum += EXP2F(v[k] - mx);
        const float anew = mx + LOG2F(sum);
#pragma unroll
        for (int k = 0; k < LL; ++k)
            alpha[k] = __uint_as_float(__builtin_amdgcn_readlane(__float_as_uint(anew), k));
    }

    // log_den = LSE(alpha + end)
    float v[LL];
#pragma unroll
    for (int k = 0; k < LL; ++k) v[k] = alpha[k] + end_t[k] * INV_LN2;
    const float mx = max9(v);
    float sum = 0.f;
#pragma unroll
    for (int k = 0; k < LL; ++k) sum += EXP2F(v[k] - mx);
    const float log_den = (mx + LOG2F(sum)) * LN2;

    if (lane == 0) {
        const int l0 = lb[0];
        const float score = start_t[l0] + fb[l0] + partial + end_t[lb[cnt - 1]];
        nll_out[b] = log_den - score;
    }
}

__global__ __launch_bounds__(64, 1)
void mean_kernel(const float* __restrict__ nll, float* __restrict__ out) {
    float v = nll[threadIdx.x];
#pragma unroll
    for (int off = 1; off < 64; off <<= 1)
        v += __shfl_xor(v, off);
    if (threadIdx.x == 0) out[0] = v * (1.0f / BB);
}

extern "C" void kernel_launch(void* const* d_in, const int* in_sizes, int n_in,
                              void* d_out, int out_size, void* d_ws, size_t ws_size,
                              hipStream_t stream) {
    const float* hidden = (const float*)d_in[0];
    const float* W      = (const float*)d_in[1];
    const float* bias   = (const float*)d_in[2];
    const float* startT = (const float*)d_in[3];
    const float* endT   = (const float*)d_in[4];
    const float* trans  = (const float*)d_in[5];
    const int*   labels = (const int*)d_in[6];
    const int*   mask   = (const int*)d_in[7];

    float* feats = (float*)d_ws;                       // B*S*L fp32 = 1.18 MB
    float* nll   = feats + (size_t)BB * SS * LL;       // 64 fp32
    float* Q     = nll + 64;                           // B*NC*81 fp32 = 664 KB

    feats_kernel<<<dim3(1024), dim3(256), 0, stream>>>(hidden, W, bias, feats);
    crf_chunk_kernel<<<dim3(BB * NC), dim3(192), 0, stream>>>(feats, trans, mask, Q);
    crf_combine_kernel<<<dim3(BB), dim3(64), 0, stream>>>(feats, Q, startT, endT, trans, labels, mask, nll);
    mean_kernel<<<dim3(1), dim3(64), 0, stream>>>(nll, (float*)d_out);
}